// Round 6
// baseline (104.306 us; speedup 1.0000x reference)
//
#include <hip/hip_runtime.h>
#include <math.h>

#define BB 8
#define NN 64
#define SS 128
#define DD 512
#define HH 8
#define DKK 64
#define NSENT (BB * NN)          // 512
#define SENT_STRIDE (SS * DD)    // 65536 floats per sentence of x / out

// d_ws layout (floats)
#define WK_OFF 0                          // wk_t[8][512]        (16 KB)
#define XB_OFF 4096                       // xbar[512][8][512]   (8 MB)
#define Z_OFF  (XB_OFF + NSENT * HH * DD) // z[512][512]         (1 MB)
#define YY_OFF (Z_OFF + NSENT * DD)       // y[512][512]         (1 MB)

// ---------------------------------------------------------------------------
// K0: fold Wk with sent_q: wk_t[h][d] = sum_k Wk[d, h*64+k] * sent_q[h,k]
// (bk is softmax-shift-invariant; Wq/bq dead: token softmax is over a singleton)
// ---------------------------------------------------------------------------
__global__ void precompute_wk(const float* __restrict__ Wk,
                              const float* __restrict__ sq,
                              float* __restrict__ wk_t) {
    const int d = threadIdx.x;
    const int h = blockIdx.x;
    const float4* wrow = (const float4*)(Wk + (size_t)d * DD + h * DKK);
    const float4* sqv  = (const float4*)(sq + h * DKK);
    float acc = 0.f;
#pragma unroll
    for (int k = 0; k < DKK / 4; ++k) {
        float4 w = wrow[k], q = sqv[k];
        acc += w.x * q.x + w.y * q.y + w.z * q.z + w.w * q.w;
    }
    wk_t[h * DD + d] = acc;
}

// ---------------------------------------------------------------------------
// KA: fused exp-weights + xbar, one block per sentence. 512 thr, 4 KB LDS,
// 2 barriers total.
//  ph1: wave w owns tokens w*16..w*16+15; dot x[s]·wk_eff[:,h] via shfl tree;
//       wl[h][s] = mask ? exp(score/8) : 0
//  ph2: thread t owns dim t; acc[h] += wl[h][s]*x[s][t], 8-deep reg prefetch;
//       xbar[sent][h][t] = acc[h] / sum_s wl[h][s]
// ---------------------------------------------------------------------------
__global__ __launch_bounds__(512)
void ka_xbar(const float* __restrict__ x, const int* __restrict__ mask,
             const float* __restrict__ wk_t, float* __restrict__ xbar)
{
    __shared__ float wl[HH][SS];   // 4 KB
    __shared__ float rsh[HH];

    const int sent = blockIdx.x;
    const int t    = threadIdx.x;
    const int wave = t >> 6;
    const int lane = t & 63;
    const float* xs = x + (size_t)sent * SENT_STRIDE;

    // wk fragments: lane owns dims d0..d0+7 for all 8 heads (64 VGPRs)
    const int d0 = lane * 8;
    float4 wkA[HH], wkB[HH];
#pragma unroll
    for (int h = 0; h < HH; ++h) {
        wkA[h] = *(const float4*)(wk_t + h * DD + d0);
        wkB[h] = *(const float4*)(wk_t + h * DD + d0 + 4);
    }
    const int hsel = lane & 7;

    // ---- ph1: 16 tokens per wave, 2 at a time for load ILP ----
    for (int j = 0; j < 16; j += 2) {
        const int s0 = wave * 16 + j;
        const float* xr0 = xs + (size_t)s0 * DD + d0;
        const float* xr1 = xr0 + DD;
        float4 xa0 = *(const float4*)xr0;
        float4 xb0 = *(const float4*)(xr0 + 4);
        float4 xa1 = *(const float4*)xr1;
        float4 xb1 = *(const float4*)(xr1 + 4);
        const int m0 = mask[sent * SS + s0];
        const int m1 = mask[sent * SS + s0 + 1];
        float p0[HH], p1[HH];
#pragma unroll
        for (int h = 0; h < HH; ++h) {
            p0[h] = xa0.x * wkA[h].x + xa0.y * wkA[h].y + xa0.z * wkA[h].z + xa0.w * wkA[h].w
                  + xb0.x * wkB[h].x + xb0.y * wkB[h].y + xb0.z * wkB[h].z + xb0.w * wkB[h].w;
            p1[h] = xa1.x * wkA[h].x + xa1.y * wkA[h].y + xa1.z * wkA[h].z + xa1.w * wkA[h].w
                  + xb1.x * wkB[h].x + xb1.y * wkB[h].y + xb1.z * wkB[h].z + xb1.w * wkB[h].w;
        }
#pragma unroll
        for (int off = 1; off <= 4; off <<= 1) {
#pragma unroll
            for (int h = 0; h < HH; ++h) {
                p0[h] += __shfl_xor(p0[h], off, 64);
                p1[h] += __shfl_xor(p1[h], off, 64);
            }
        }
        float v0 = p0[0], v1 = p1[0];
#pragma unroll
        for (int h = 1; h < HH; ++h) {
            v0 = (hsel == h) ? p0[h] : v0;
            v1 = (hsel == h) ? p1[h] : v1;
        }
#pragma unroll
        for (int off = 8; off <= 32; off <<= 1) {
            v0 += __shfl_xor(v0, off, 64);
            v1 += __shfl_xor(v1, off, 64);
        }
        if (lane < HH) {
            wl[lane][s0]     = m0 ? __expf(v0 * 0.125f) : 0.f;
            wl[lane][s0 + 1] = m1 ? __expf(v1 * 0.125f) : 0.f;
        }
    }
    __syncthreads();

    // ---- per-head 1/sum: wave h reduces wl[h][:] ----
    {
        float v = wl[wave][lane] + wl[wave][lane + 64];
#pragma unroll
        for (int off = 1; off <= 32; off <<= 1)
            v += __shfl_xor(v, off, 64);
        if (lane == 0) rsh[wave] = 1.0f / v;
    }
    __syncthreads();

    // ---- ph2: thread-per-dim accumulate, 8-deep double-buffered prefetch ----
    {
        const float* xp = xs + t;
        float acc[HH];
#pragma unroll
        for (int h = 0; h < HH; ++h) acc[h] = 0.f;

        float xa[8], xb[8];
#pragma unroll
        for (int j = 0; j < 8; ++j) xa[j] = xp[(size_t)j * DD];

        for (int s0 = 0; s0 < SS; s0 += 16) {
#pragma unroll
            for (int j = 0; j < 8; ++j) xb[j] = xp[(size_t)(s0 + 8 + j) * DD];
#pragma unroll
            for (int j = 0; j < 8; ++j) {
                const float xv = xa[j];
#pragma unroll
                for (int h = 0; h < HH; ++h) acc[h] += wl[h][s0 + j] * xv;
            }
            if (s0 + 16 < SS) {
#pragma unroll
                for (int j = 0; j < 8; ++j) xa[j] = xp[(size_t)(s0 + 16 + j) * DD];
            }
#pragma unroll
            for (int j = 0; j < 8; ++j) {
                const float xv = xb[j];
#pragma unroll
                for (int h = 0; h < HH; ++h) acc[h] += wl[h][s0 + 8 + j] * xv;
            }
        }
        float* xbp = xbar + (size_t)sent * (HH * DD) + t;
#pragma unroll
        for (int h = 0; h < HH; ++h)
            xbp[h * DD] = acc[h] * rsh[h];
    }
}

// ---------------------------------------------------------------------------
// KZ/KY: 16x64-tile fp32 GEMM, M=512, K=512, register-prefetched across the
// barrier. 256 blocks (32 mb x 8 nb), 256 thr, thread = (row tr, colgroup tc).
//  KZ: A=xbar (am=4096, a_nb=512 head select), B=Wv, bias=bv -> z
//  KY: A=z    (am=512,  a_nb=0),               B=Wo, bias=bo -> y
// ---------------------------------------------------------------------------
__global__ __launch_bounds__(256)
void gemm_tile(const float* __restrict__ A, const int am_stride, const int a_nb_stride,
               const float* __restrict__ B, const float* __restrict__ bias,
               float* __restrict__ C)
{
    __shared__ float As[64][17];   // [k][m]
    __shared__ float Bs[64][68];   // [k][n]

    const int nb = blockIdx.x & 7, mb = blockIdx.x >> 3;
    const int t  = threadIdx.x;
    const int tr = t >> 4, tc = t & 15;

    const float* Ab = A + (size_t)(mb * 16) * am_stride + nb * a_nb_stride
                        + (size_t)tr * am_stride + tc * 4;
    const float* Bb = B + nb * 64 + (size_t)tr * DD + tc * 4;

    float4 ar = *(const float4*)(Ab);
    float4 br0 = *(const float4*)(Bb);
    float4 br1 = *(const float4*)(Bb + 16 * DD);
    float4 br2 = *(const float4*)(Bb + 32 * DD);
    float4 br3 = *(const float4*)(Bb + 48 * DD);

    float a0 = 0.f, a1 = 0.f, a2 = 0.f, a3 = 0.f;

    for (int k0 = 0; k0 < DD; k0 += 64) {
        As[tc * 4 + 0][tr] = ar.x;
        As[tc * 4 + 1][tr] = ar.y;
        As[tc * 4 + 2][tr] = ar.z;
        As[tc * 4 + 3][tr] = ar.w;
        *(float4*)&Bs[tr +  0][tc * 4] = br0;
        *(float4*)&Bs[tr + 16][tc * 4] = br1;
        *(float4*)&Bs[tr + 32][tc * 4] = br2;
        *(float4*)&Bs[tr + 48][tc * 4] = br3;
        __syncthreads();
        if (k0 + 64 < DD) {       // prefetch next K-tile; overlaps compute below
            ar  = *(const float4*)(Ab + k0 + 64);
            br0 = *(const float4*)(Bb + (size_t)(k0 + 64) * DD);
            br1 = *(const float4*)(Bb + (size_t)(k0 + 80) * DD);
            br2 = *(const float4*)(Bb + (size_t)(k0 + 96) * DD);
            br3 = *(const float4*)(Bb + (size_t)(k0 + 112) * DD);
        }
#pragma unroll
        for (int kk = 0; kk < 64; ++kk) {
            const float av = As[kk][tr];
            const float4 bv4 = *(const float4*)&Bs[kk][tc * 4];
            a0 += av * bv4.x; a1 += av * bv4.y; a2 += av * bv4.z; a3 += av * bv4.w;
        }
        __syncthreads();
    }

    const float4 bb = *(const float4*)(bias + nb * 64 + tc * 4);
    float4 o; o.x = a0 + bb.x; o.y = a1 + bb.y; o.z = a2 + bb.z; o.w = a3 + bb.w;
    *(float4*)(C + (size_t)(mb * 16 + tr) * DD + nb * 64 + tc * 4) = o;
}

// ---------------------------------------------------------------------------
// KB: broadcast y[sent] to all 128 token rows of out. 2048 blocks x 256 thr.
// ---------------------------------------------------------------------------
__global__ __launch_bounds__(256)
void kb_bcast(const float* __restrict__ y, float* __restrict__ outp)
{
    const int sent = blockIdx.x >> 2, q = blockIdx.x & 3;
    const int c4 = threadIdx.x & 127;       // float4 column 0..127
    const int rr = threadIdx.x >> 7;        // 0..1
    const float4 yv = *(const float4*)(y + (size_t)sent * DD + c4 * 4);
    float* w0 = outp + (size_t)sent * SENT_STRIDE + (size_t)(q * 32 + rr) * DD + c4 * 4;
#pragma unroll
    for (int i = 0; i < 16; ++i)
        *(float4*)(w0 + (size_t)(i * 2) * DD) = yv;
}

extern "C" void kernel_launch(void* const* d_in, const int* in_sizes, int n_in,
                              void* d_out, int out_size, void* d_ws, size_t ws_size,
                              hipStream_t stream) {
    const float* x    = (const float*)d_in[0];
    const int*   mask = (const int*)  d_in[1];
    // d_in[2]=Wq, d_in[3]=bq dead (token softmax over singleton); d_in[5]=bk shift-invariant
    const float* Wk   = (const float*)d_in[4];
    const float* Wv   = (const float*)d_in[6];
    const float* bv   = (const float*)d_in[7];
    const float* sq   = (const float*)d_in[8];
    const float* Wo   = (const float*)d_in[9];
    const float* bo   = (const float*)d_in[10];
    float* out = (float*)d_out;
    float* ws  = (float*)d_ws;

    float* wk_t = ws + WK_OFF;
    float* xbar = ws + XB_OFF;
    float* z    = ws + Z_OFF;
    float* y    = ws + YY_OFF;

    precompute_wk<<<HH, DD, 0, stream>>>(Wk, sq, wk_t);
    ka_xbar<<<NSENT, 512, 0, stream>>>(x, mask, wk_t, xbar);
    gemm_tile<<<256, 256, 0, stream>>>(xbar, HH * DD, DD, Wv, bv, z);
    gemm_tile<<<256, 256, 0, stream>>>(z, DD, 0, Wo, bo, y);
    kb_bcast<<<NSENT * 4, 256, 0, stream>>>(y, out);
}

// Round 7
// 103.841 us; speedup vs baseline: 1.0045x; 1.0045x over previous
//
#include <hip/hip_runtime.h>
#include <math.h>

#define BB 8
#define NN 64
#define SS 128
#define DD 512
#define HH 8
#define DKK 64
#define NSENT (BB * NN)          // 512
#define SENT_STRIDE (SS * DD)    // 65536 floats per sentence of x / out

// d_ws layout (floats)
#define WK_OFF 0                          // wk_t[8][512]        (16 KB)
#define XB_OFF 4096                       // xbar[512][8][512]   (8 MB)
#define Z_OFF  (XB_OFF + NSENT * HH * DD) // z[512][512]         (1 MB)
#define YY_OFF (Z_OFF + NSENT * DD)       // y[512][512]         (1 MB)

// ---------------------------------------------------------------------------
// K0: fold Wk with sent_q: wk_t[h][d] = sum_k Wk[d, h*64+k] * sent_q[h,k]
// (bk is softmax-shift-invariant; Wq/bq dead: token softmax is over a singleton)
// ---------------------------------------------------------------------------
__global__ void precompute_wk(const float* __restrict__ Wk,
                              const float* __restrict__ sq,
                              float* __restrict__ wk_t) {
    const int d = threadIdx.x;
    const int h = blockIdx.x;
    const float4* wrow = (const float4*)(Wk + (size_t)d * DD + h * DKK);
    const float4* sqv  = (const float4*)(sq + h * DKK);
    float acc = 0.f;
#pragma unroll
    for (int k = 0; k < DKK / 4; ++k) {
        float4 w = wrow[k], q = sqv[k];
        acc += w.x * q.x + w.y * q.y + w.z * q.z + w.w * q.w;
    }
    wk_t[h * DD + d] = acc;
}

// ---------------------------------------------------------------------------
// KA: fused exp-weights + xbar, one block per sentence. 512 thr, 4 KB LDS,
// 2 barriers total.
//  ph1: wave w owns tokens w*16..w*16+15; dot x[s]·wk_eff[:,h] via shfl tree;
//       wl[h][s] = mask ? exp(score/8) : 0
//  ph2: thread t owns dim t; acc[h] += wl[h][s]*x[s][t], 8-deep reg prefetch;
//       xbar[sent][h][t] = acc[h] / sum_s wl[h][s]
// ---------------------------------------------------------------------------
__global__ __launch_bounds__(512)
void ka_xbar(const float* __restrict__ x, const int* __restrict__ mask,
             const float* __restrict__ wk_t, float* __restrict__ xbar)
{
    __shared__ float wl[HH][SS];   // 4 KB
    __shared__ float rsh[HH];

    const int sent = blockIdx.x;
    const int t    = threadIdx.x;
    const int wave = t >> 6;
    const int lane = t & 63;
    const float* xs = x + (size_t)sent * SENT_STRIDE;

    // wk fragments: lane owns dims d0..d0+7 for all 8 heads (64 VGPRs)
    const int d0 = lane * 8;
    float4 wkA[HH], wkB[HH];
#pragma unroll
    for (int h = 0; h < HH; ++h) {
        wkA[h] = *(const float4*)(wk_t + h * DD + d0);
        wkB[h] = *(const float4*)(wk_t + h * DD + d0 + 4);
    }
    const int hsel = lane & 7;

    // ---- ph1: 16 tokens per wave, 2 at a time for load ILP ----
    for (int j = 0; j < 16; j += 2) {
        const int s0 = wave * 16 + j;
        const float* xr0 = xs + (size_t)s0 * DD + d0;
        const float* xr1 = xr0 + DD;
        float4 xa0 = *(const float4*)xr0;
        float4 xb0 = *(const float4*)(xr0 + 4);
        float4 xa1 = *(const float4*)xr1;
        float4 xb1 = *(const float4*)(xr1 + 4);
        const int m0 = mask[sent * SS + s0];
        const int m1 = mask[sent * SS + s0 + 1];
        float p0[HH], p1[HH];
#pragma unroll
        for (int h = 0; h < HH; ++h) {
            p0[h] = xa0.x * wkA[h].x + xa0.y * wkA[h].y + xa0.z * wkA[h].z + xa0.w * wkA[h].w
                  + xb0.x * wkB[h].x + xb0.y * wkB[h].y + xb0.z * wkB[h].z + xb0.w * wkB[h].w;
            p1[h] = xa1.x * wkA[h].x + xa1.y * wkA[h].y + xa1.z * wkA[h].z + xa1.w * wkA[h].w
                  + xb1.x * wkB[h].x + xb1.y * wkB[h].y + xb1.z * wkB[h].z + xb1.w * wkB[h].w;
        }
#pragma unroll
        for (int off = 1; off <= 4; off <<= 1) {
#pragma unroll
            for (int h = 0; h < HH; ++h) {
                p0[h] += __shfl_xor(p0[h], off, 64);
                p1[h] += __shfl_xor(p1[h], off, 64);
            }
        }
        float v0 = p0[0], v1 = p1[0];
#pragma unroll
        for (int h = 1; h < HH; ++h) {
            v0 = (hsel == h) ? p0[h] : v0;
            v1 = (hsel == h) ? p1[h] : v1;
        }
#pragma unroll
        for (int off = 8; off <= 32; off <<= 1) {
            v0 += __shfl_xor(v0, off, 64);
            v1 += __shfl_xor(v1, off, 64);
        }
        if (lane < HH) {
            wl[lane][s0]     = m0 ? __expf(v0 * 0.125f) : 0.f;
            wl[lane][s0 + 1] = m1 ? __expf(v1 * 0.125f) : 0.f;
        }
    }
    __syncthreads();

    // ---- per-head 1/sum: wave h reduces wl[h][:] ----
    {
        float v = wl[wave][lane] + wl[wave][lane + 64];
#pragma unroll
        for (int off = 1; off <= 32; off <<= 1)
            v += __shfl_xor(v, off, 64);
        if (lane == 0) rsh[wave] = 1.0f / v;
    }
    __syncthreads();

    // ---- ph2: thread-per-dim accumulate, 8-deep double-buffered prefetch ----
    {
        const float* xp = xs + t;
        float acc[HH];
#pragma unroll
        for (int h = 0; h < HH; ++h) acc[h] = 0.f;

        float xa[8], xb[8];
#pragma unroll
        for (int j = 0; j < 8; ++j) xa[j] = xp[(size_t)j * DD];

        for (int s0 = 0; s0 < SS; s0 += 16) {
#pragma unroll
            for (int j = 0; j < 8; ++j) xb[j] = xp[(size_t)(s0 + 8 + j) * DD];
#pragma unroll
            for (int j = 0; j < 8; ++j) {
                const float xv = xa[j];
#pragma unroll
                for (int h = 0; h < HH; ++h) acc[h] += wl[h][s0 + j] * xv;
            }
            if (s0 + 16 < SS) {
#pragma unroll
                for (int j = 0; j < 8; ++j) xa[j] = xp[(size_t)(s0 + 16 + j) * DD];
            }
#pragma unroll
            for (int j = 0; j < 8; ++j) {
                const float xv = xb[j];
#pragma unroll
                for (int h = 0; h < HH; ++h) acc[h] += wl[h][s0 + 8 + j] * xv;
            }
        }
        float* xbp = xbar + (size_t)sent * (HH * DD) + t;
#pragma unroll
        for (int h = 0; h < HH; ++h)
            xbp[h * DD] = acc[h] * rsh[h];
    }
}

// ---------------------------------------------------------------------------
// KZ/KY: 16x64-tile fp32 GEMM, M=512, K=512, register-prefetched across the
// barrier. 256 blocks (32 mb x 8 nb), 256 thr, thread = (row tr, colgroup tc).
//  KZ: A=xbar (am=4096, a_nb=512 head select), B=Wv, bias=bv -> z
//  KY: A=z    (am=512,  a_nb=0),               B=Wo, bias=bo -> y
// ---------------------------------------------------------------------------
__global__ __launch_bounds__(256)
void gemm_tile(const float* __restrict__ A, const int am_stride, const int a_nb_stride,
               const float* __restrict__ B, const float* __restrict__ bias,
               float* __restrict__ C)
{
    __shared__ float As[64][17];   // [k][m]
    __shared__ float Bs[64][68];   // [k][n]

    const int nb = blockIdx.x & 7, mb = blockIdx.x >> 3;
    const int t  = threadIdx.x;
    const int tr = t >> 4, tc = t & 15;

    const float* Ab = A + (size_t)(mb * 16) * am_stride + nb * a_nb_stride
                        + (size_t)tr * am_stride + tc * 4;
    const float* Bb = B + nb * 64 + (size_t)tr * DD + tc * 4;

    float4 ar = *(const float4*)(Ab);
    float4 br0 = *(const float4*)(Bb);
    float4 br1 = *(const float4*)(Bb + 16 * DD);
    float4 br2 = *(const float4*)(Bb + 32 * DD);
    float4 br3 = *(const float4*)(Bb + 48 * DD);

    float a0 = 0.f, a1 = 0.f, a2 = 0.f, a3 = 0.f;

    for (int k0 = 0; k0 < DD; k0 += 64) {
        As[tc * 4 + 0][tr] = ar.x;
        As[tc * 4 + 1][tr] = ar.y;
        As[tc * 4 + 2][tr] = ar.z;
        As[tc * 4 + 3][tr] = ar.w;
        *(float4*)&Bs[tr +  0][tc * 4] = br0;
        *(float4*)&Bs[tr + 16][tc * 4] = br1;
        *(float4*)&Bs[tr + 32][tc * 4] = br2;
        *(float4*)&Bs[tr + 48][tc * 4] = br3;
        __syncthreads();
        if (k0 + 64 < DD) {       // prefetch next K-tile; overlaps compute below
            ar  = *(const float4*)(Ab + k0 + 64);
            br0 = *(const float4*)(Bb + (size_t)(k0 + 64) * DD);
            br1 = *(const float4*)(Bb + (size_t)(k0 + 80) * DD);
            br2 = *(const float4*)(Bb + (size_t)(k0 + 96) * DD);
            br3 = *(const float4*)(Bb + (size_t)(k0 + 112) * DD);
        }
#pragma unroll
        for (int kk = 0; kk < 64; ++kk) {
            const float av = As[kk][tr];
            const float4 bv4 = *(const float4*)&Bs[kk][tc * 4];
            a0 += av * bv4.x; a1 += av * bv4.y; a2 += av * bv4.z; a3 += av * bv4.w;
        }
        __syncthreads();
    }

    const float4 bb = *(const float4*)(bias + nb * 64 + tc * 4);
    float4 o; o.x = a0 + bb.x; o.y = a1 + bb.y; o.z = a2 + bb.z; o.w = a3 + bb.w;
    *(float4*)(C + (size_t)(mb * 16 + tr) * DD + nb * 64 + tc * 4) = o;
}

// ---------------------------------------------------------------------------
// KB: broadcast y[sent] to all 128 token rows of out. 2048 blocks x 256 thr.
// ---------------------------------------------------------------------------
__global__ __launch_bounds__(256)
void kb_bcast(const float* __restrict__ y, float* __restrict__ outp)
{
    const int sent = blockIdx.x >> 2, q = blockIdx.x & 3;
    const int c4 = threadIdx.x & 127;       // float4 column 0..127
    const int rr = threadIdx.x >> 7;        // 0..1
    const float4 yv = *(const float4*)(y + (size_t)sent * DD + c4 * 4);
    float* w0 = outp + (size_t)sent * SENT_STRIDE + (size_t)(q * 32 + rr) * DD + c4 * 4;
#pragma unroll
    for (int i = 0; i < 16; ++i)
        *(float4*)(w0 + (size_t)(i * 2) * DD) = yv;
}

extern "C" void kernel_launch(void* const* d_in, const int* in_sizes, int n_in,
                              void* d_out, int out_size, void* d_ws, size_t ws_size,
                              hipStream_t stream) {
    const float* x    = (const float*)d_in[0];
    const int*   mask = (const int*)  d_in[1];
    // d_in[2]=Wq, d_in[3]=bq dead (token softmax over singleton); d_in[5]=bk shift-invariant
    const float* Wk   = (const float*)d_in[4];
    const float* Wv   = (const float*)d_in[6];
    const float* bv   = (const float*)d_in[7];
    const float* sq   = (const float*)d_in[8];
    const float* Wo   = (const float*)d_in[9];
    const float* bo   = (const float*)d_in[10];
    float* out = (float*)d_out;
    float* ws  = (float*)d_ws;

    float* wk_t = ws + WK_OFF;
    float* xbar = ws + XB_OFF;
    float* z    = ws + Z_OFF;
    float* y    = ws + YY_OFF;

    precompute_wk<<<HH, DD, 0, stream>>>(Wk, sq, wk_t);
    ka_xbar<<<NSENT, 512, 0, stream>>>(x, mask, wk_t, xbar);
    gemm_tile<<<256, 256, 0, stream>>>(xbar, HH * DD, DD, Wv, bv, z);
    gemm_tile<<<256, 256, 0, stream>>>(z, DD, 0, Wo, bo, y);
    kb_bcast<<<NSENT * 4, 256, 0, stream>>>(y, out);
}